// Round 2
// baseline (387.579 us; speedup 1.0000x reference)
//
#include <hip/hip_runtime.h>
#include <hip/hip_bf16.h>
#include <math.h>

// Problem constants (fixed by setup_inputs)
constexpr int B_ = 32;
constexpr int C_ = 256;
constexpr int N_ = 64;
constexpr int S_ = 64;
constexpr int NPIX = N_ * N_;   // 4096
constexpr int P_ = 2080;        // valid (upper-triangle) proposals per video
constexpr int TPB = 33;         // 64-proposal tiles per video (33*64 >= 2080)
constexpr int NQ = TPB * B_;    // 1056 inter-query blocks
constexpr int TOTAL = NQ + S_;  // 1120 blocks total

#define T_V_INV 10.0f
#define T_Q_INV 10.0f
#define NEG_IOU 0.5f

typedef __attribute__((ext_vector_type(8))) short short8;
typedef __attribute__((ext_vector_type(4))) float f32x4;

static __device__ __forceinline__ unsigned short f2bf(float x) {
  __hip_bfloat16 h = __float2bfloat16(x);
  unsigned short u;
  __builtin_memcpy(&u, &h, sizeof(u));
  return u;
}

// Manually-overlaid LDS: the three phases (inter-query / inter-video / finale)
// are mutually exclusive per block section, so union them (compiler does NOT
// auto-union separate __shared__ declarations).
union SMem {
  struct {                       // inter-query path (~34.3 KB)
    short8 afr[32 * 64];         // 32 KB bf16 A-fragments
    float rns[S_];
    int ssc[S_];
    float scr[4][S_];            // ssq partials, later part-fold
  } q;
  struct {                       // inter-video path (~4.4 KB)
    float vh[C_];
    float rns[S_];
    float scr[4][S_];
    float red[4];
    float bval[256];
    int bidx[256];
  } v;
  struct {                       // finale (4 KB)
    f32x4 m[16][16];
  } f;
};

// ---------------------------------------------------------------------------
// Single fused kernel. Blocks [0,NQ): triangle-packed inter-query MFMA GEMM
// (self-contained: sentence norms + A-fragments computed per block from
// sents, scatter from nt, triangle index inverted analytically). Blocks
// [NQ, NQ+64): inter-video loss (self-contained likewise). Last block to
// finish (device-scope counter) performs the final reduction + both losses.
// ---------------------------------------------------------------------------
__global__ __launch_bounds__(256) void k_all(
    const float* __restrict__ V, const float* __restrict__ sents,
    const int* __restrict__ nt, const float* __restrict__ iou,
    float* __restrict__ partials, float* __restrict__ pos_score,
    float* __restrict__ loss_vid, int* __restrict__ cnt,
    float* __restrict__ out) {
  __shared__ SMem sm;
  __shared__ int s_last;
  int tid = threadIdx.x;
  int bx = blockIdx.x;

  if (bx < NQ) {
    // ===================== inter-query =====================
    if (tid < S_) {  // scatter_idx from nt
      int cum = 0, res = 0;
      for (int b = 0; b < B_; b++) {
        int nb = nt[b];
        if (tid >= cum && tid < cum + nb) res = b;
        cum += nb;
      }
      sm.q.ssc[tid] = res;
    }
    // Phase A: per-sentence sum-of-squares (thread = (sentence, 64-ch chunk))
    int sa = tid & 63, chA = tid >> 6;
    const f32x4* sp = (const f32x4*)(sents + sa * C_ + chA * 64);
    f32x4 val[16];
    float ssqA = 0.0f;
    #pragma unroll
    for (int k = 0; k < 16; k++) {
      val[k] = sp[k];
      ssqA += val[k][0] * val[k][0] + val[k][1] * val[k][1] +
              val[k][2] * val[k][2] + val[k][3] * val[k][3];
    }
    sm.q.scr[chA][sa] = ssqA;
    __syncthreads();
    if (tid < S_) {
      float tot = sm.q.scr[0][tid] + sm.q.scr[1][tid] +
                  sm.q.scr[2][tid] + sm.q.scr[3][tid];
      sm.q.rns[tid] = 1.0f / fmaxf(sqrtf(tot), 1e-12f);
    }
    __syncthreads();
    // Phase B: build bf16 A-fragments from the registers of phase A.
    // Layout identical to r1: entry (ks*4+mt)*64 + q*16 + m, elem j = c&7.
    {
      float rn = sm.q.rns[sa];
      int mt0 = sa >> 4, m0 = sa & 15;
      #pragma unroll
      for (int u = 0; u < 8; u++) {
        int c0 = chA * 64 + u * 8;
        int ks = c0 >> 5, qq = (c0 >> 3) & 3;
        f32x4 a = val[u * 2], b = val[u * 2 + 1];
        short8 e;
        e[0] = (short)f2bf(a[0] * rn); e[1] = (short)f2bf(a[1] * rn);
        e[2] = (short)f2bf(a[2] * rn); e[3] = (short)f2bf(a[3] * rn);
        e[4] = (short)f2bf(b[0] * rn); e[5] = (short)f2bf(b[1] * rn);
        e[6] = (short)f2bf(b[2] * rn); e[7] = (short)f2bf(b[3] * rn);
        sm.q.afr[((ks * 4 + mt0) << 6) + (qq * 16 + m0)] = e;
      }
    }
    __syncthreads();

    // MFMA path (r1-proven inner loop)
    int vid = bx / TPB, blk = bx % TPB;
    int w = tid >> 6, lane = tid & 63;
    int n = lane & 15, q = lane >> 4;
    int t = blk * 64 + w * 16 + n;
    bool valid = (t < P_);
    int tt = valid ? t : (P_ - 1);
    // invert triangle index: find row r with cum(r) <= tt < cum(r+1),
    // cum(r) = (129r - r^2)/2; closed form + exact fixup
    float disc = 16641.0f - 8.0f * (float)tt;
    int r = (int)((129.0f - sqrtf(disc)) * 0.5f);
    int cum = (129 * r - r * r) >> 1;
    if (tt < cum) {
      r -= 1; cum = (129 * r - r * r) >> 1;
    } else {
      int cn = (129 * (r + 1) - (r + 1) * (r + 1)) >> 1;
      if (tt >= cn) { r += 1; cum = cn; }
    }
    int pix = r * 64 + (r + (tt - cum));

    const float* vb = V + (size_t)vid * C_ * NPIX + pix;
    const float* vbq = vb + (size_t)(q * 8) * NPIX;

    // Preload all 64 V values (c = ks*32 + q*8 + j) — single load burst.
    float vv[64];
    #pragma unroll
    for (int ks = 0; ks < 8; ks++) {
      #pragma unroll
      for (int j = 0; j < 8; j++) {
        vv[ks * 8 + j] = vbq[(size_t)(ks * 32 + j) * NPIX];
      }
    }

    f32x4 acc[4] = {f32x4{0,0,0,0}, f32x4{0,0,0,0}, f32x4{0,0,0,0}, f32x4{0,0,0,0}};
    float ssq = 0.0f;

    #pragma unroll
    for (int ks = 0; ks < 8; ks++) {
      short8 bfrag;
      #pragma unroll
      for (int j = 0; j < 8; j++) {
        float x = vv[ks * 8 + j];
        ssq = fmaf(x, x, ssq);
        bfrag[j] = (short)f2bf(x);
      }
      #pragma unroll
      for (int mt = 0; mt < 4; mt++) {
        short8 a = sm.q.afr[(ks * 4 + mt) * 64 + lane];
        acc[mt] = __builtin_amdgcn_mfma_f32_16x16x32_bf16(a, bfrag, acc[mt], 0, 0, 0);
      }
    }

    ssq += __shfl_xor(ssq, 16);
    ssq += __shfl_xor(ssq, 32);
    float rs = T_Q_INV / fmaxf(sqrtf(ssq), 1e-12f);

    // Epilogue: D layout col(pixel)=lane&15, sentence s = mt*16 + q*4 + rr
    #pragma unroll
    for (int mt = 0; mt < 4; mt++) {
      #pragma unroll
      for (int rr = 0; rr < 4; rr++) {
        int s = mt * 16 + q * 4 + rr;
        float e = valid ? __expf(acc[mt][rr] * rs) : 0.0f;
        if (valid && sm.q.ssc[s] == vid) {
          if (iou[s * NPIX + pix] > NEG_IOU) e = 0.0f; // positive -> excluded
        }
        e += __shfl_xor(e, 1);
        e += __shfl_xor(e, 2);
        e += __shfl_xor(e, 4);
        e += __shfl_xor(e, 8); // summed over this wave's 16 proposals
        if (n == 0) sm.q.scr[w][s] = e;
      }
    }
    __syncthreads();
    if (tid < S_) {
      partials[(size_t)bx * S_ + tid] =
          sm.q.scr[0][tid] + sm.q.scr[1][tid] + sm.q.scr[2][tid] + sm.q.scr[3][tid];
    }
  } else {
    // ===================== inter-video (one block per sentence) ============
    int s = bx - NQ;
    int cum = 0, b = 0;
    for (int i = 0; i < B_; i++) {   // scatter for this sentence
      int nb = nt[i];
      if (s >= cum && s < cum + nb) b = i;
      cum += nb;
    }
    // top-1 valid pixel (ties -> lowest flat index)
    float bv = -1.0f;
    int bi = 0x7fffffff;
    for (int p0 = tid; p0 < NPIX; p0 += 256) {
      int rr = p0 >> 6, cc = p0 & 63;
      if (cc >= rr) {
        float x = iou[s * NPIX + p0];
        if (x > bv) { bv = x; bi = p0; }
      }
    }
    sm.v.bval[tid] = bv; sm.v.bidx[tid] = bi;
    __syncthreads();
    for (int st = 128; st; st >>= 1) {
      if (tid < st) {
        float ov = sm.v.bval[tid + st]; int oi = sm.v.bidx[tid + st];
        if (ov > sm.v.bval[tid] || (ov == sm.v.bval[tid] && oi < sm.v.bidx[tid])) {
          sm.v.bval[tid] = ov; sm.v.bidx[tid] = oi;
        }
      }
      __syncthreads();
    }
    int pix = sm.v.bidx[0];

    // Phase A: sentence norms (registers reused for the dot below)
    int t = tid & 63, chA = tid >> 6;
    const f32x4* sp = (const f32x4*)(sents + t * C_ + chA * 64);
    f32x4 val[16];
    float ssqA = 0.0f;
    #pragma unroll
    for (int k = 0; k < 16; k++) {
      val[k] = sp[k];
      ssqA += val[k][0] * val[k][0] + val[k][1] * val[k][1] +
              val[k][2] * val[k][2] + val[k][3] * val[k][3];
    }
    sm.v.scr[chA][t] = ssqA;

    // this sentence's video column
    float vraw = V[((size_t)b * C_ + tid) * NPIX + pix];
    float ss = vraw * vraw;
    #pragma unroll
    for (int o = 32; o; o >>= 1) ss += __shfl_xor(ss, o);
    if ((tid & 63) == 0) sm.v.red[tid >> 6] = ss;
    __syncthreads();
    if (tid < S_) {
      float totS = sm.v.scr[0][tid] + sm.v.scr[1][tid] +
                   sm.v.scr[2][tid] + sm.v.scr[3][tid];
      sm.v.rns[tid] = 1.0f / fmaxf(sqrtf(totS), 1e-12f);
    }
    float totV = sm.v.red[0] + sm.v.red[1] + sm.v.red[2] + sm.v.red[3];
    float rnv = 1.0f / fmaxf(sqrtf(totV), 1e-12f);
    sm.v.vh[tid] = vraw * rnv;
    __syncthreads();
    float rnt = sm.v.rns[t];
    float pd = 0.0f;
    #pragma unroll
    for (int k = 0; k < 16; k++) {
      int c = chA * 64 + k * 4;
      pd += sm.v.vh[c] * val[k][0] + sm.v.vh[c + 1] * val[k][1] +
            sm.v.vh[c + 2] * val[k][2] + sm.v.vh[c + 3] * val[k][3];
    }
    pd *= rnt;
    sm.v.scr[chA][t] = pd;
    __syncthreads();
    if (tid < S_) {
      float dot = sm.v.scr[0][tid] + sm.v.scr[1][tid] +
                  sm.v.scr[2][tid] + sm.v.scr[3][tid];
      if (tid == s) pos_score[s] = dot;
      float pos = __shfl(dot, s);
      float e = (tid == s) ? 0.0f : __expf(dot * T_V_INV);
      #pragma unroll
      for (int o = 32; o; o >>= 1) e += __shfl_xor(e, o);
      if (tid == 0) {
        float pp = pos * T_V_INV;
        loss_vid[s] = -(pp - logf(__expf(pp) + e));
      }
    }
  }

  // ===================== completion tail (last block -> finale) ============
  __threadfence();           // device-scope release of this block's stores
  __syncthreads();
  if (tid == 0) s_last = (atomicAdd(cnt, 1) == TOTAL - 1) ? 1 : 0;
  __syncthreads();
  if (s_last) {
    __threadfence();         // acquire: all other blocks' stores visible
    const f32x4* p4 = (const f32x4*)partials;
    int s4 = tid & 15, g = tid >> 4;   // 16 row-groups x 16 col-quads
    f32x4 a = {0.0f, 0.0f, 0.0f, 0.0f};
    for (int k = 0; k < 66; k++)       // 16*66 = 1056 rows
      a += p4[(size_t)(g + (k << 4)) * 16 + s4];
    sm.f.m[g][s4] = a;
    __syncthreads();
    if (tid < S_) {
      float neg = 0.0f;
      #pragma unroll
      for (int g2 = 0; g2 < 16; g2++) neg += sm.f.m[g2][tid >> 2][tid & 3];
      float p = pos_score[tid] * T_Q_INV;
      float lq = -(p - logf(__expf(p) + neg));
      float lv = loss_vid[tid];
      #pragma unroll
      for (int o = 32; o; o >>= 1) {
        lq += __shfl_xor(lq, o);
        lv += __shfl_xor(lv, o);
      }
      if (tid == 0) {
        out[0] = lv / (float)S_;
        out[1] = lq / (float)S_;
      }
    }
  }
}

// ---------------------------------------------------------------------------
extern "C" void kernel_launch(void* const* d_in, const int* in_sizes, int n_in,
                              void* d_out, int out_size, void* d_ws, size_t ws_size,
                              hipStream_t stream) {
  const float* V     = (const float*)d_in[0]; // [B,C,N,N]
  const float* sents = (const float*)d_in[1]; // [S,C]
  const int*   nt    = (const int*)d_in[2];   // [B]
  const float* iou   = (const float*)d_in[3]; // [S,N,N]
  // d_in[4] = mask2d: structural triu — resolved statically (as in reference)

  float* ws = (float*)d_ws;
  float* partials  = ws;                         // NQ*64 floats (16B-aligned)
  float* pos_score = ws + (size_t)NQ * S_;       // 64
  float* loss_vid  = pos_score + S_;             // 64
  int*   cnt       = (int*)(loss_vid + S_);      // 1 (completion counter)

  hipMemsetAsync(cnt, 0, sizeof(int), stream);   // zero the poisoned counter
  k_all<<<TOTAL, 256, 0, stream>>>(V, sents, nt, iou, partials, pos_score,
                                   loss_vid, cnt, (float*)d_out);
}

// Round 3
// 220.248 us; speedup vs baseline: 1.7597x; 1.7597x over previous
//
#include <hip/hip_runtime.h>
#include <hip/hip_bf16.h>
#include <math.h>

// Problem constants (fixed by setup_inputs)
constexpr int B_ = 32;
constexpr int C_ = 256;
constexpr int N_ = 64;
constexpr int S_ = 64;
constexpr int NPIX = N_ * N_;   // 4096
constexpr int P_ = 2080;        // valid (upper-triangle) proposals per video
constexpr int TPB = 33;         // 64-proposal tiles per video (33*64 = 2112 >= 2080)
constexpr int NQ = TPB * B_;    // 1056 inter-query blocks

#define T_V_INV 10.0f
#define T_Q_INV 10.0f
#define NEG_IOU 0.5f

typedef __attribute__((ext_vector_type(8))) short short8;
typedef __attribute__((ext_vector_type(4))) float f32x4;

static __device__ __forceinline__ unsigned short f2bf(float x) {
  __hip_bfloat16 h = __float2bfloat16(x);
  unsigned short u;
  __builtin_memcpy(&u, &h, sizeof(u));
  return u;
}

// ---------------------------------------------------------------------------
// K1 setup: blocks 0..63 = per-sentence (normalize feats -> sf_t fp32 + bf16
// MFMA A-fragments; top-1 valid pixel from iou). Block 64 = scatter_idx +
// triangle flat-index -> pixel table.
// ---------------------------------------------------------------------------
__global__ __launch_bounds__(256) void k_setup(
    const float* __restrict__ sents, const float* __restrict__ iou,
    const int* __restrict__ nt,
    float* __restrict__ sf_t, unsigned short* __restrict__ sf_frag,
    int* __restrict__ scatter, int* __restrict__ top_pix,
    int* __restrict__ tab) {
  int bid = blockIdx.x, tid = threadIdx.x;
  __shared__ float wsum[4];
  __shared__ float bval[256];
  __shared__ int bidx[256];

  if (bid < S_) {
    int s = bid, c = tid;
    float v = sents[s * C_ + c];
    float ss = v * v;
    #pragma unroll
    for (int o = 32; o; o >>= 1) ss += __shfl_xor(ss, o);
    if ((c & 63) == 0) wsum[c >> 6] = ss;
    __syncthreads();
    float tot = wsum[0] + wsum[1] + wsum[2] + wsum[3];
    float rn = 1.0f / fmaxf(sqrtf(tot), 1e-12f);
    float o = v * rn;
    sf_t[c * S_ + s] = o;
    // A-fragment layout: A[m=s][k=c], lane = quad*16 + (s&15), elem j = c&7
    int ks = c >> 5, q = (c >> 3) & 3, j = c & 7;
    int mt = s >> 4, m = s & 15;
    sf_frag[((ks * 4 + mt) * 64 + (q * 16 + m)) * 8 + j] = f2bf(o);

    // top-1 valid pixel (ties -> lowest flat index)
    float bv = -1.0f;
    int bi = 0x7fffffff;
    for (int pix = tid; pix < NPIX; pix += 256) {
      int r = pix >> 6, c0 = pix & 63;
      if (c0 >= r) {
        float x = iou[s * NPIX + pix];
        if (x > bv) { bv = x; bi = pix; }
      }
    }
    bval[tid] = bv; bidx[tid] = bi;
    __syncthreads();
    for (int st = 128; st; st >>= 1) {
      if (tid < st) {
        float ov = bval[tid + st]; int oi = bidx[tid + st];
        if (ov > bval[tid] || (ov == bval[tid] && oi < bidx[tid])) {
          bval[tid] = ov; bidx[tid] = oi;
        }
      }
      __syncthreads();
    }
    if (tid == 0) top_pix[s] = bidx[0];
  } else {
    if (tid < S_) {
      int cum = 0, res = 0;
      for (int b = 0; b < B_; b++) {
        int nb = nt[b];
        if (tid >= cum && tid < cum + nb) res = b;
        cum += nb;
      }
      scatter[tid] = res;
    }
    // triangle flat-index -> pixel table
    for (int pix = tid; pix < NPIX; pix += 256) {
      int r = pix >> 6, c0 = pix & 63;
      if (c0 >= r) {
        int t = r * 64 - (r * (r - 1)) / 2 + (c0 - r);
        tab[t] = pix;
      }
    }
  }
}

// ---------------------------------------------------------------------------
// K2 main: blocks [0,NQ) = triangle-packed inter-query MFMA GEMM. Per-ks
// inline V loads (compiler-balanced pressure, R0-proven loop) + A-fragments
// read directly from global (32 KB total, L2-resident, coalesced 1KB/wave) --
// no 32 KB LDS stage, so LDS ~3 KB and the occupancy cap doubles to 32
// waves/CU. Blocks [NQ, NQ+64) = inter-video loss (unchanged from R1).
// ---------------------------------------------------------------------------
__global__ __launch_bounds__(256) void k_main(
    const float* __restrict__ V, const float* __restrict__ iou,
    const short8* __restrict__ Afrag, const float* __restrict__ sf_t,
    const int* __restrict__ scatter, const int* __restrict__ top_pix,
    const int* __restrict__ tab,
    float* __restrict__ partials, float* __restrict__ pos_score,
    float* __restrict__ loss_vid) {
  __shared__ int ssc[S_];
  __shared__ float part[4][S_];
  __shared__ float vh[C_];
  __shared__ float red[4];
  __shared__ float pdm[4][S_];

  int tid = threadIdx.x;

  if (blockIdx.x < NQ) {
    // ============ inter-query path ============
    if (tid < S_) ssc[tid] = scatter[tid];
    __syncthreads();

    int v = blockIdx.x / TPB, blk = blockIdx.x % TPB;
    int w = tid >> 6, lane = tid & 63;
    int n = lane & 15, q = lane >> 4;
    int t = blk * 64 + w * 16 + n;
    bool valid = (t < P_);
    int tt = valid ? t : (P_ - 1);
    int pix = tab[tt];

    const float* vbq = V + (size_t)v * C_ * NPIX + (size_t)(q * 8) * NPIX + pix;

    f32x4 acc[4] = {f32x4{0,0,0,0}, f32x4{0,0,0,0}, f32x4{0,0,0,0}, f32x4{0,0,0,0}};
    float ssq = 0.0f;

    #pragma unroll
    for (int ks = 0; ks < 8; ks++) {
      short8 bfrag;
      #pragma unroll
      for (int j = 0; j < 8; j++) {
        float x = vbq[(size_t)(ks * 32 + j) * NPIX]; // c = ks*32 + q*8 + j
        ssq = fmaf(x, x, ssq);
        bfrag[j] = (short)f2bf(x);
      }
      #pragma unroll
      for (int mt = 0; mt < 4; mt++) {
        short8 a = Afrag[(ks * 4 + mt) * 64 + lane];
        acc[mt] = __builtin_amdgcn_mfma_f32_16x16x32_bf16(a, bfrag, acc[mt], 0, 0, 0);
      }
    }

    ssq += __shfl_xor(ssq, 16);
    ssq += __shfl_xor(ssq, 32);
    float rs = T_Q_INV / fmaxf(sqrtf(ssq), 1e-12f);

    // Epilogue: D layout col(pixel)=lane&15, sentence s = mt*16 + q*4 + rr
    #pragma unroll
    for (int mt = 0; mt < 4; mt++) {
      #pragma unroll
      for (int rr = 0; rr < 4; rr++) {
        int s = mt * 16 + q * 4 + rr;
        float e = valid ? __expf(acc[mt][rr] * rs) : 0.0f;
        if (valid && ssc[s] == v) {
          if (iou[s * NPIX + pix] > NEG_IOU) e = 0.0f; // positive -> excluded
        }
        e += __shfl_xor(e, 1);
        e += __shfl_xor(e, 2);
        e += __shfl_xor(e, 4);
        e += __shfl_xor(e, 8); // summed over this wave's 16 proposals
        if (n == 0) part[w][s] = e;
      }
    }
    __syncthreads();
    if (tid < S_) {
      partials[(size_t)blockIdx.x * S_ + tid] =
          part[0][tid] + part[1][tid] + part[2][tid] + part[3][tid];
    }
  } else {
    // ============ inter-video path (one block per sentence) ============
    int s = blockIdx.x - NQ;
    int b = scatter[s];
    int pix = top_pix[s];
    float v = V[((size_t)b * C_ + tid) * NPIX + pix];
    float ss = v * v;
    #pragma unroll
    for (int o = 32; o; o >>= 1) ss += __shfl_xor(ss, o);
    if ((tid & 63) == 0) red[tid >> 6] = ss;
    __syncthreads();
    float tot = red[0] + red[1] + red[2] + red[3];
    float rn = 1.0f / fmaxf(sqrtf(tot), 1e-12f);
    vh[tid] = v * rn;
    __syncthreads();
    int so = tid & 63, chunk = tid >> 6;
    float pd = 0.0f;
    #pragma unroll 8
    for (int c = chunk * 64; c < chunk * 64 + 64; c++)
      pd = fmaf(vh[c], sf_t[c * S_ + so], pd);
    pdm[chunk][so] = pd;
    __syncthreads();
    if (tid < S_) {
      float dot = pdm[0][tid] + pdm[1][tid] + pdm[2][tid] + pdm[3][tid];
      if (tid == s) pos_score[s] = dot;
      float pos = __shfl(dot, s);
      float e = (tid == s) ? 0.0f : __expf(dot * T_V_INV);
      #pragma unroll
      for (int o = 32; o; o >>= 1) e += __shfl_xor(e, o);
      if (tid == 0) {
        float pp = pos * T_V_INV;
        loss_vid[s] = -(pp - logf(__expf(pp) + e));
      }
    }
  }
}

// ---------------------------------------------------------------------------
// K3 final (merged reduce + loss): 1 block x 1024 threads. Phase 1: float4-
// vectorized fold of partials[NQ][64] -> neg[s]. Phase 2: both losses.
// ---------------------------------------------------------------------------
__global__ __launch_bounds__(1024) void k_fin(
    const float* __restrict__ partials, const float* __restrict__ pos_score,
    const float* __restrict__ loss_vid, float* __restrict__ out) {
  int tid = threadIdx.x;
  __shared__ f32x4 m[64][16];
  const f32x4* p4 = (const f32x4*)partials;
  int s4 = tid & 15, g = tid >> 4; // g in [0,64)
  f32x4 a = {0.0f, 0.0f, 0.0f, 0.0f};
  #pragma unroll 4
  for (int i = g; i < NQ; i += 64) a += p4[i * 16 + s4];
  m[g][s4] = a;
  __syncthreads();
  if (tid < S_) {
    int q4 = tid >> 2, e4 = tid & 3;
    float neg = 0.0f;
    #pragma unroll
    for (int g2 = 0; g2 < 64; g2++) neg += m[g2][q4][e4];
    float p = pos_score[tid] * T_Q_INV;
    float lq = -(p - logf(__expf(p) + neg));
    float lv = loss_vid[tid];
    #pragma unroll
    for (int o = 32; o; o >>= 1) {
      lq += __shfl_xor(lq, o);
      lv += __shfl_xor(lv, o);
    }
    if (tid == 0) {
      out[0] = lv / (float)S_;
      out[1] = lq / (float)S_;
    }
  }
}

// ---------------------------------------------------------------------------
extern "C" void kernel_launch(void* const* d_in, const int* in_sizes, int n_in,
                              void* d_out, int out_size, void* d_ws, size_t ws_size,
                              hipStream_t stream) {
  const float* V     = (const float*)d_in[0]; // [B,C,N,N]
  const float* sents = (const float*)d_in[1]; // [S,C]
  const int*   nt    = (const int*)d_in[2];   // [B]
  const float* iou   = (const float*)d_in[3]; // [S,N,N]
  // d_in[4] = mask2d: structural triu — resolved statically (as in reference)

  float* ws = (float*)d_ws;
  float*          sf_t    = ws;                            // 16384 floats
  unsigned short* sf_frag = (unsigned short*)(ws + 16384); // 16384 bf16 (8192 f)
  int*   scatter   = (int*)(ws + 16384 + 8192);            // 64
  int*   top_pix   = scatter + S_;                         // 64
  float* pos_score = (float*)(top_pix + S_);               // 64
  float* loss_vid  = pos_score + S_;                       // 64
  int*   tab       = (int*)(loss_vid + S_);                // 2112 (pads to 16B)
  float* partials  = (float*)(tab + TPB * 64);             // NQ*64 floats, 16B-aligned

  k_setup<<<S_ + 1, 256, 0, stream>>>(sents, iou, nt, sf_t, sf_frag, scatter,
                                      top_pix, tab);
  k_main <<<NQ + S_, 256, 0, stream>>>(V, iou, (const short8*)sf_frag, sf_t,
                                       scatter, top_pix, tab, partials,
                                       pos_score, loss_vid);
  k_fin  <<<1, 1024, 0, stream>>>(partials, pos_score, loss_vid, (float*)d_out);
}

// Round 4
// 217.757 us; speedup vs baseline: 1.7799x; 1.0114x over previous
//
#include <hip/hip_runtime.h>
#include <hip/hip_bf16.h>
#include <math.h>

// Problem constants (fixed by setup_inputs)
constexpr int B_ = 32;
constexpr int C_ = 256;
constexpr int N_ = 64;
constexpr int S_ = 64;
constexpr int NPIX = N_ * N_;   // 4096
constexpr int P_ = 2080;        // valid (upper-triangle) proposals per video
constexpr int GTOT = B_ * P_;   // 66560 total (video, proposal) pairs
constexpr int NQ = GTOT / 64;   // 1040 inter-query blocks (64 pairs each, exact)

#define T_V_INV 10.0f
#define T_Q_INV 10.0f
#define NEG_IOU 0.5f

typedef __attribute__((ext_vector_type(8))) short short8;
typedef __attribute__((ext_vector_type(4))) float f32x4;

static __device__ __forceinline__ unsigned short f2bf(float x) {
  __hip_bfloat16 h = __float2bfloat16(x);
  unsigned short u;
  __builtin_memcpy(&u, &h, sizeof(u));
  return u;
}

// ---------------------------------------------------------------------------
// K1 setup: blocks 0..63 = per-sentence (normalize feats -> sf_t fp32 + bf16
// MFMA A-fragments; top-1 valid pixel from iou). Block 64 = scatter_idx +
// triangle flat-index -> pixel table (tab[t] = r*64+col, t in [0,2080)).
// ---------------------------------------------------------------------------
__global__ __launch_bounds__(256) void k_setup(
    const float* __restrict__ sents, const float* __restrict__ iou,
    const int* __restrict__ nt,
    float* __restrict__ sf_t, unsigned short* __restrict__ sf_frag,
    int* __restrict__ scatter, int* __restrict__ top_pix,
    int* __restrict__ tab) {
  int bid = blockIdx.x, tid = threadIdx.x;
  __shared__ float wsum[4];
  __shared__ float bval[256];
  __shared__ int bidx[256];

  if (bid < S_) {
    int s = bid, c = tid;
    float v = sents[s * C_ + c];
    float ss = v * v;
    #pragma unroll
    for (int o = 32; o; o >>= 1) ss += __shfl_xor(ss, o);
    if ((c & 63) == 0) wsum[c >> 6] = ss;
    __syncthreads();
    float tot = wsum[0] + wsum[1] + wsum[2] + wsum[3];
    float rn = 1.0f / fmaxf(sqrtf(tot), 1e-12f);
    float o = v * rn;
    sf_t[c * S_ + s] = o;
    // A-fragment layout: A[m=s][k=c], lane = quad*16 + (s&15), elem j = c&7
    int ks = c >> 5, q = (c >> 3) & 3, j = c & 7;
    int mt = s >> 4, m = s & 15;
    sf_frag[((ks * 4 + mt) * 64 + (q * 16 + m)) * 8 + j] = f2bf(o);

    // top-1 valid pixel (ties -> lowest flat index)
    float bv = -1.0f;
    int bi = 0x7fffffff;
    for (int pix = tid; pix < NPIX; pix += 256) {
      int r = pix >> 6, c0 = pix & 63;
      if (c0 >= r) {
        float x = iou[s * NPIX + pix];
        if (x > bv) { bv = x; bi = pix; }
      }
    }
    bval[tid] = bv; bidx[tid] = bi;
    __syncthreads();
    for (int st = 128; st; st >>= 1) {
      if (tid < st) {
        float ov = bval[tid + st]; int oi = bidx[tid + st];
        if (ov > bval[tid] || (ov == bval[tid] && oi < bidx[tid])) {
          bval[tid] = ov; bidx[tid] = oi;
        }
      }
      __syncthreads();
    }
    if (tid == 0) top_pix[s] = bidx[0];
  } else {
    if (tid < S_) {
      int cum = 0, res = 0;
      for (int b = 0; b < B_; b++) {
        int nb = nt[b];
        if (tid >= cum && tid < cum + nb) res = b;
        cum += nb;
      }
      scatter[tid] = res;
    }
    // triangle flat-index -> pixel table
    for (int pix = tid; pix < NPIX; pix += 256) {
      int r = pix >> 6, c0 = pix & 63;
      if (c0 >= r) {
        int t = r * 64 - (r * (r - 1)) / 2 + (c0 - r);
        tab[t] = pix;
      }
    }
  }
}

// ---------------------------------------------------------------------------
// K2 main: blocks [0,NQ) = inter-query MFMA GEMM over a FLAT (video,proposal)
// index g = bx*64 + w*16 + n in [0,66560): exact coverage, zero masked lanes,
// 1040 blocks (better tail balance than 1056 padded). R1-proven inner
// structure: 32 KB LDS A-fragment stage + vv[64] register preload burst.
// Blocks [NQ, NQ+64) = inter-video loss.
// ---------------------------------------------------------------------------
__global__ __launch_bounds__(256) void k_main(
    const float* __restrict__ V, const float* __restrict__ iou,
    const short8* __restrict__ Afrag, const float* __restrict__ sf_t,
    const int* __restrict__ scatter, const int* __restrict__ top_pix,
    const int* __restrict__ tab,
    float* __restrict__ partials, float* __restrict__ pos_score,
    float* __restrict__ loss_vid) {
  __shared__ int ssc[S_];
  __shared__ float part[4][S_];
  __shared__ short8 afr[32 * 64];   // 32 KB staged A-fragments
  __shared__ float vh[C_];
  __shared__ float red[4];
  __shared__ float pdm[4][S_];

  int tid = threadIdx.x;

  if (blockIdx.x < NQ) {
    // ============ inter-query path ============
    if (tid < S_) ssc[tid] = scatter[tid];
    for (int i = tid; i < 32 * 64; i += 256) afr[i] = Afrag[i];
    __syncthreads();

    int w = tid >> 6, lane = tid & 63;
    int n = lane & 15, q = lane >> 4;
    int g = blockIdx.x * 64 + w * 16 + n;  // flat (video, proposal), all valid
    int vid = g / P_;                       // magic-mul division
    int t = g - vid * P_;
    int pix = tab[t];

    const float* vbq = V + ((size_t)vid * C_ + q * 8) * NPIX + pix;

    // Preload all 64 V values (c = ks*32 + q*8 + j) — single load burst.
    float vv[64];
    #pragma unroll
    for (int ks = 0; ks < 8; ks++) {
      #pragma unroll
      for (int j = 0; j < 8; j++) {
        vv[ks * 8 + j] = vbq[(size_t)(ks * 32 + j) * NPIX];
      }
    }

    f32x4 acc[4] = {f32x4{0,0,0,0}, f32x4{0,0,0,0}, f32x4{0,0,0,0}, f32x4{0,0,0,0}};
    float ssq = 0.0f;

    #pragma unroll
    for (int ks = 0; ks < 8; ks++) {
      short8 bfrag;
      #pragma unroll
      for (int j = 0; j < 8; j++) {
        float x = vv[ks * 8 + j];
        ssq = fmaf(x, x, ssq);
        bfrag[j] = (short)f2bf(x);
      }
      #pragma unroll
      for (int mt = 0; mt < 4; mt++) {
        short8 a = afr[(ks * 4 + mt) * 64 + lane];
        acc[mt] = __builtin_amdgcn_mfma_f32_16x16x32_bf16(a, bfrag, acc[mt], 0, 0, 0);
      }
    }

    // ssq: lanes {n, n+16, n+32, n+48} hold the 4 channel-quarters of pixel n
    ssq += __shfl_xor(ssq, 16);
    ssq += __shfl_xor(ssq, 32);
    float rs = T_Q_INV / fmaxf(sqrtf(ssq), 1e-12f);

    // Epilogue: D layout col(pixel)=lane&15, sentence s = mt*16 + q*4 + rr
    #pragma unroll
    for (int mt = 0; mt < 4; mt++) {
      #pragma unroll
      for (int rr = 0; rr < 4; rr++) {
        int s = mt * 16 + q * 4 + rr;
        float e = __expf(acc[mt][rr] * rs);
        if (ssc[s] == vid) {
          if (iou[s * NPIX + pix] > NEG_IOU) e = 0.0f; // positive -> excluded
        }
        e += __shfl_xor(e, 1);
        e += __shfl_xor(e, 2);
        e += __shfl_xor(e, 4);
        e += __shfl_xor(e, 8); // summed over this wave's 16 proposals
        if (n == 0) part[w][s] = e;
      }
    }
    __syncthreads();
    if (tid < S_) {
      partials[(size_t)blockIdx.x * S_ + tid] =
          part[0][tid] + part[1][tid] + part[2][tid] + part[3][tid];
    }
  } else {
    // ============ inter-video path (one block per sentence) ============
    int s = blockIdx.x - NQ;
    int b = scatter[s];
    int pix = top_pix[s];
    float v = V[((size_t)b * C_ + tid) * NPIX + pix];
    float ss = v * v;
    #pragma unroll
    for (int o = 32; o; o >>= 1) ss += __shfl_xor(ss, o);
    if ((tid & 63) == 0) red[tid >> 6] = ss;
    __syncthreads();
    float tot = red[0] + red[1] + red[2] + red[3];
    float rn = 1.0f / fmaxf(sqrtf(tot), 1e-12f);
    vh[tid] = v * rn;
    __syncthreads();
    int so = tid & 63, chunk = tid >> 6;
    float pd = 0.0f;
    #pragma unroll 8
    for (int c = chunk * 64; c < chunk * 64 + 64; c++)
      pd = fmaf(vh[c], sf_t[c * S_ + so], pd);
    pdm[chunk][so] = pd;
    __syncthreads();
    if (tid < S_) {
      float dot = pdm[0][tid] + pdm[1][tid] + pdm[2][tid] + pdm[3][tid];
      if (tid == s) pos_score[s] = dot;
      float pos = __shfl(dot, s);
      float e = (tid == s) ? 0.0f : __expf(dot * T_V_INV);
      #pragma unroll
      for (int o = 32; o; o >>= 1) e += __shfl_xor(e, o);
      if (tid == 0) {
        float pp = pos * T_V_INV;
        loss_vid[s] = -(pp - logf(__expf(pp) + e));
      }
    }
  }
}

// ---------------------------------------------------------------------------
// K3 final (merged reduce + loss): 1 block x 1024 threads. Phase 1: float4-
// vectorized fold of partials[NQ][64] -> neg[s]. Phase 2: both losses.
// ---------------------------------------------------------------------------
__global__ __launch_bounds__(1024) void k_fin(
    const float* __restrict__ partials, const float* __restrict__ pos_score,
    const float* __restrict__ loss_vid, float* __restrict__ out) {
  int tid = threadIdx.x;
  __shared__ f32x4 m[64][16];
  const f32x4* p4 = (const f32x4*)partials;
  int s4 = tid & 15, g = tid >> 4; // g in [0,64)
  f32x4 a = {0.0f, 0.0f, 0.0f, 0.0f};
  #pragma unroll 4
  for (int i = g; i < NQ; i += 64) a += p4[i * 16 + s4];
  m[g][s4] = a;
  __syncthreads();
  if (tid < S_) {
    int q4 = tid >> 2, e4 = tid & 3;
    float neg = 0.0f;
    #pragma unroll
    for (int g2 = 0; g2 < 64; g2++) neg += m[g2][q4][e4];
    float p = pos_score[tid] * T_Q_INV;
    float lq = -(p - logf(__expf(p) + neg));
    float lv = loss_vid[tid];
    #pragma unroll
    for (int o = 32; o; o >>= 1) {
      lq += __shfl_xor(lq, o);
      lv += __shfl_xor(lv, o);
    }
    if (tid == 0) {
      out[0] = lv / (float)S_;
      out[1] = lq / (float)S_;
    }
  }
}

// ---------------------------------------------------------------------------
extern "C" void kernel_launch(void* const* d_in, const int* in_sizes, int n_in,
                              void* d_out, int out_size, void* d_ws, size_t ws_size,
                              hipStream_t stream) {
  const float* V     = (const float*)d_in[0]; // [B,C,N,N]
  const float* sents = (const float*)d_in[1]; // [S,C]
  const int*   nt    = (const int*)d_in[2];   // [B]
  const float* iou   = (const float*)d_in[3]; // [S,N,N]
  // d_in[4] = mask2d: structural triu — resolved statically (as in reference)

  float* ws = (float*)d_ws;
  float*          sf_t    = ws;                            // 16384 floats
  unsigned short* sf_frag = (unsigned short*)(ws + 16384); // 16384 bf16 (8192 f)
  int*   scatter   = (int*)(ws + 16384 + 8192);            // 64
  int*   top_pix   = scatter + S_;                         // 64
  float* pos_score = (float*)(top_pix + S_);               // 64
  float* loss_vid  = pos_score + S_;                       // 64
  int*   tab       = (int*)(loss_vid + S_);                // 2080 pad to 2112 (16B)
  float* partials  = (float*)(tab + 2112);                 // NQ*64 floats, 16B-aligned

  k_setup<<<S_ + 1, 256, 0, stream>>>(sents, iou, nt, sf_t, sf_frag, scatter,
                                      top_pix, tab);
  k_main <<<NQ + S_, 256, 0, stream>>>(V, iou, (const short8*)sf_frag, sf_t,
                                       scatter, top_pix, tab, partials,
                                       pos_score, loss_vid);
  k_fin  <<<1, 1024, 0, stream>>>(partials, pos_score, loss_vid, (float*)d_out);
}

// Round 5
// 212.713 us; speedup vs baseline: 1.8221x; 1.0237x over previous
//
#include <hip/hip_runtime.h>
#include <hip/hip_bf16.h>
#include <math.h>

// Problem constants (fixed by setup_inputs)
constexpr int B_ = 32;
constexpr int C_ = 256;
constexpr int N_ = 64;
constexpr int S_ = 64;
constexpr int NPIX = N_ * N_;   // 4096
constexpr int P_ = 2080;        // valid (upper-triangle) proposals per video
constexpr int TPB = 33;         // 64-proposal tiles per video (33*64 = 2112 >= 2080)
constexpr int NQ = TPB * B_;    // 1056 inter-query blocks

#define T_V_INV 10.0f
#define T_Q_INV 10.0f
#define NEG_IOU 0.5f

typedef __attribute__((ext_vector_type(8))) short short8;
typedef __attribute__((ext_vector_type(4))) float f32x4;

static __device__ __forceinline__ unsigned short f2bf(float x) {
  __hip_bfloat16 h = __float2bfloat16(x);
  unsigned short u;
  __builtin_memcpy(&u, &h, sizeof(u));
  return u;
}

// ---------------------------------------------------------------------------
// K1 setup: blocks 0..63 = per-sentence (normalize feats -> sf_t fp32 + bf16
// MFMA A-fragments; top-1 valid pixel from iou). Block 64 = scatter_idx +
// triangle flat-index -> pixel table (tab[t] = r*64+col in row-major triangle
// order, t in [0, 2080)).
// ---------------------------------------------------------------------------
__global__ __launch_bounds__(256) void k_setup(
    const float* __restrict__ sents, const float* __restrict__ iou,
    const int* __restrict__ nt,
    float* __restrict__ sf_t, unsigned short* __restrict__ sf_frag,
    int* __restrict__ scatter, int* __restrict__ top_pix,
    int* __restrict__ tab) {
  int bid = blockIdx.x, tid = threadIdx.x;
  __shared__ float wsum[4];
  __shared__ float bval[256];
  __shared__ int bidx[256];

  if (bid < S_) {
    int s = bid, c = tid;
    float v = sents[s * C_ + c];
    float ss = v * v;
    #pragma unroll
    for (int o = 32; o; o >>= 1) ss += __shfl_xor(ss, o);
    if ((c & 63) == 0) wsum[c >> 6] = ss;
    __syncthreads();
    float tot = wsum[0] + wsum[1] + wsum[2] + wsum[3];
    float rn = 1.0f / fmaxf(sqrtf(tot), 1e-12f);
    float o = v * rn;
    sf_t[c * S_ + s] = o;
    // A-fragment layout: A[m=s][k=c], lane = quad*16 + (s&15), elem j = c&7
    int ks = c >> 5, q = (c >> 3) & 3, j = c & 7;
    int mt = s >> 4, m = s & 15;
    sf_frag[((ks * 4 + mt) * 64 + (q * 16 + m)) * 8 + j] = f2bf(o);

    // top-1 valid pixel (ties -> lowest flat index)
    float bv = -1.0f;
    int bi = 0x7fffffff;
    for (int pix = tid; pix < NPIX; pix += 256) {
      int r = pix >> 6, c0 = pix & 63;
      if (c0 >= r) {
        float x = iou[s * NPIX + pix];
        if (x > bv) { bv = x; bi = pix; }
      }
    }
    bval[tid] = bv; bidx[tid] = bi;
    __syncthreads();
    for (int st = 128; st; st >>= 1) {
      if (tid < st) {
        float ov = bval[tid + st]; int oi = bidx[tid + st];
        if (ov > bval[tid] || (ov == bval[tid] && oi < bidx[tid])) {
          bval[tid] = ov; bidx[tid] = oi;
        }
      }
      __syncthreads();
    }
    if (tid == 0) top_pix[s] = bidx[0];
  } else {
    if (tid < S_) {
      int cum = 0, res = 0;
      for (int b = 0; b < B_; b++) {
        int nb = nt[b];
        if (tid >= cum && tid < cum + nb) res = b;
        cum += nb;
      }
      scatter[tid] = res;
    }
    // triangle flat-index -> pixel table
    for (int pix = tid; pix < NPIX; pix += 256) {
      int r = pix >> 6, c0 = pix & 63;
      if (c0 >= r) {
        int t = r * 64 - (r * (r - 1)) / 2 + (c0 - r);
        tab[t] = pix;
      }
    }
  }
}

// ---------------------------------------------------------------------------
// K2 main: blocks [0,NQ) = triangle-packed inter-query MFMA GEMM. Each block
// handles 64 consecutive valid proposals of one video (no dead triangle
// lanes). V loads fully preloaded into 64 regs/thread (one vmcnt burst);
// A-fragments staged once per block into LDS. Blocks [NQ, NQ+64) = the
// inter-video loss (one block per sentence, unchanged).
// ---------------------------------------------------------------------------
__global__ __launch_bounds__(256) void k_main(
    const float* __restrict__ V, const float* __restrict__ iou,
    const short8* __restrict__ Afrag, const float* __restrict__ sf_t,
    const int* __restrict__ scatter, const int* __restrict__ top_pix,
    const int* __restrict__ tab,
    float* __restrict__ partials, float* __restrict__ pos_score,
    float* __restrict__ loss_vid) {
  __shared__ int ssc[S_];
  __shared__ float part[4][S_];
  __shared__ short8 afr[32 * 64];   // 32 KB staged A-fragments
  __shared__ float vh[C_];
  __shared__ float red[4];
  __shared__ float pdm[4][S_];

  int tid = threadIdx.x;

  if (blockIdx.x < NQ) {
    // ============ inter-query path ============
    if (tid < S_) ssc[tid] = scatter[tid];
    for (int i = tid; i < 32 * 64; i += 256) afr[i] = Afrag[i];
    __syncthreads();

    int v = blockIdx.x / TPB, blk = blockIdx.x % TPB;
    int w = tid >> 6, lane = tid & 63;
    int n = lane & 15, q = lane >> 4;
    int t = blk * 64 + w * 16 + n;
    bool valid = (t < P_);
    int tt = valid ? t : (P_ - 1);
    int pix = tab[tt];

    const float* vb = V + (size_t)v * C_ * NPIX + pix;
    const float* vbq = vb + (size_t)(q * 8) * NPIX;

    // Preload all 64 V values (c = ks*32 + q*8 + j) — single load burst.
    float vv[64];
    #pragma unroll
    for (int ks = 0; ks < 8; ks++) {
      #pragma unroll
      for (int j = 0; j < 8; j++) {
        vv[ks * 8 + j] = vbq[(size_t)(ks * 32 + j) * NPIX];
      }
    }

    f32x4 acc[4] = {f32x4{0,0,0,0}, f32x4{0,0,0,0}, f32x4{0,0,0,0}, f32x4{0,0,0,0}};
    float ssq = 0.0f;

    #pragma unroll
    for (int ks = 0; ks < 8; ks++) {
      short8 bfrag;
      #pragma unroll
      for (int j = 0; j < 8; j++) {
        float x = vv[ks * 8 + j];
        ssq = fmaf(x, x, ssq);
        bfrag[j] = (short)f2bf(x);
      }
      #pragma unroll
      for (int mt = 0; mt < 4; mt++) {
        short8 a = afr[(ks * 4 + mt) * 64 + lane];
        acc[mt] = __builtin_amdgcn_mfma_f32_16x16x32_bf16(a, bfrag, acc[mt], 0, 0, 0);
      }
    }

    ssq += __shfl_xor(ssq, 16);
    ssq += __shfl_xor(ssq, 32);
    float rs = T_Q_INV / fmaxf(sqrtf(ssq), 1e-12f);

    // Epilogue: D layout col(pixel)=lane&15, sentence s = mt*16 + q*4 + rr
    #pragma unroll
    for (int mt = 0; mt < 4; mt++) {
      #pragma unroll
      for (int rr = 0; rr < 4; rr++) {
        int s = mt * 16 + q * 4 + rr;
        float e = valid ? __expf(acc[mt][rr] * rs) : 0.0f;
        if (valid && ssc[s] == v) {
          if (iou[s * NPIX + pix] > NEG_IOU) e = 0.0f; // positive -> excluded
        }
        e += __shfl_xor(e, 1);
        e += __shfl_xor(e, 2);
        e += __shfl_xor(e, 4);
        e += __shfl_xor(e, 8); // summed over this wave's 16 proposals
        if (n == 0) part[w][s] = e;
      }
    }
    __syncthreads();
    if (tid < S_) {
      partials[(size_t)blockIdx.x * S_ + tid] =
          part[0][tid] + part[1][tid] + part[2][tid] + part[3][tid];
    }
  } else {
    // ============ inter-video path (one block per sentence) ============
    int s = blockIdx.x - NQ;
    int b = scatter[s];
    int pix = top_pix[s];
    float v = V[((size_t)b * C_ + tid) * NPIX + pix];
    float ss = v * v;
    #pragma unroll
    for (int o = 32; o; o >>= 1) ss += __shfl_xor(ss, o);
    if ((tid & 63) == 0) red[tid >> 6] = ss;
    __syncthreads();
    float tot = red[0] + red[1] + red[2] + red[3];
    float rn = 1.0f / fmaxf(sqrtf(tot), 1e-12f);
    vh[tid] = v * rn;
    __syncthreads();
    int so = tid & 63, chunk = tid >> 6;
    float pd = 0.0f;
    #pragma unroll 8
    for (int c = chunk * 64; c < chunk * 64 + 64; c++)
      pd = fmaf(vh[c], sf_t[c * S_ + so], pd);
    pdm[chunk][so] = pd;
    __syncthreads();
    if (tid < S_) {
      float dot = pdm[0][tid] + pdm[1][tid] + pdm[2][tid] + pdm[3][tid];
      if (tid == s) pos_score[s] = dot;
      float pos = __shfl(dot, s);
      float e = (tid == s) ? 0.0f : __expf(dot * T_V_INV);
      #pragma unroll
      for (int o = 32; o; o >>= 1) e += __shfl_xor(e, o);
      if (tid == 0) {
        float pp = pos * T_V_INV;
        loss_vid[s] = -(pp - logf(__expf(pp) + e));
      }
    }
  }
}

// ---------------------------------------------------------------------------
// K3 final (merged reduce + loss): 1 block x 1024 threads. Phase 1: float4-
// vectorized fold of partials[NQ][64] -> neg[s] (64 rowgroups x 16 col4groups,
// all loads coalesced). Phase 2: both losses, write the two means.
// ---------------------------------------------------------------------------
__global__ __launch_bounds__(1024) void k_fin(
    const float* __restrict__ partials, const float* __restrict__ pos_score,
    const float* __restrict__ loss_vid, float* __restrict__ out) {
  int tid = threadIdx.x;
  __shared__ f32x4 m[64][16];
  const f32x4* p4 = (const f32x4*)partials;
  int s4 = tid & 15, g = tid >> 4; // g in [0,64)
  f32x4 a = {0.0f, 0.0f, 0.0f, 0.0f};
  #pragma unroll 4
  for (int i = g; i < NQ; i += 64) a += p4[i * 16 + s4];
  m[g][s4] = a;
  __syncthreads();
  if (tid < S_) {
    int q4 = tid >> 2, e4 = tid & 3;
    float neg = 0.0f;
    #pragma unroll
    for (int g2 = 0; g2 < 64; g2++) neg += m[g2][q4][e4];
    float p = pos_score[tid] * T_Q_INV;
    float lq = -(p - logf(__expf(p) + neg));
    float lv = loss_vid[tid];
    #pragma unroll
    for (int o = 32; o; o >>= 1) {
      lq += __shfl_xor(lq, o);
      lv += __shfl_xor(lv, o);
    }
    if (tid == 0) {
      out[0] = lv / (float)S_;
      out[1] = lq / (float)S_;
    }
  }
}

// ---------------------------------------------------------------------------
extern "C" void kernel_launch(void* const* d_in, const int* in_sizes, int n_in,
                              void* d_out, int out_size, void* d_ws, size_t ws_size,
                              hipStream_t stream) {
  const float* V     = (const float*)d_in[0]; // [B,C,N,N]
  const float* sents = (const float*)d_in[1]; // [S,C]
  const int*   nt    = (const int*)d_in[2];   // [B]
  const float* iou   = (const float*)d_in[3]; // [S,N,N]
  // d_in[4] = mask2d: structural triu — resolved statically (as in reference)

  float* ws = (float*)d_ws;
  float*          sf_t    = ws;                            // 16384 floats
  unsigned short* sf_frag = (unsigned short*)(ws + 16384); // 16384 bf16 (8192 f)
  int*   scatter   = (int*)(ws + 16384 + 8192);            // 64
  int*   top_pix   = scatter + S_;                         // 64
  float* pos_score = (float*)(top_pix + S_);               // 64
  float* loss_vid  = pos_score + S_;                       // 64
  int*   tab       = (int*)(loss_vid + S_);                // 2112 (pads to 16B)
  float* partials  = (float*)(tab + TPB * 64);             // NQ*64 floats, 16B-aligned

  k_setup<<<S_ + 1, 256, 0, stream>>>(sents, iou, nt, sf_t, sf_frag, scatter,
                                      top_pix, tab);
  k_main <<<NQ + S_, 256, 0, stream>>>(V, iou, (const short8*)sf_frag, sf_t,
                                       scatter, top_pix, tab, partials,
                                       pos_score, loss_vid);
  k_fin  <<<1, 1024, 0, stream>>>(partials, pos_score, loss_vid, (float*)d_out);
}